// Round 9
// baseline (131.777 us; speedup 1.0000x reference)
//
#include <hip/hip_runtime.h>
#include <math.h>

#define Nn 65536

typedef short s16x8 __attribute__((ext_vector_type(8)));
typedef float f32x4 __attribute__((ext_vector_type(4)));
typedef unsigned int u32;

__device__ __forceinline__ unsigned short f2bf(float x) {
    u32 u = __float_as_uint(x);
    u += 0x7FFFu + ((u >> 16) & 1u);
    return (unsigned short)(u >> 16);
}

// argmax over row s of the 4x4 type_matching (first max wins, matches jnp.argmax)
__device__ __forceinline__ int best_t_for(const float* __restrict__ tm, int s, float* mOut) {
    float m = tm[s * 4];
    int am = 0;
#pragma unroll
    for (int j = 1; j < 4; ++j) {
        float v = tm[s * 4 + j];
        if (v > m) { m = v; am = j; }
    }
    if (mOut) *mOut = m;
    return am;
}

// ============ k_prepw: weight convert ONLY (96 blocks) ============
// fp32 [D][H] -> bf16 fragment-linear for the 12 live (s, best_t) matrices
__global__ void k_prepw(const float* __restrict__ tm,
                        const float* __restrict__ W1, const float* __restrict__ W2,
                        const float* __restrict__ C1, unsigned short* __restrict__ wbf) {
    int u = blockIdx.x * 256 + threadIdx.x;      // 0..24575
    int mat = u >> 11;
    int rr = u & 2047;
    int f = rr >> 6, lane = rr & 63;
    int kk = f >> 3, n8 = f & 7;
    int q = lane >> 4, l15 = lane & 15;
    int sm = mat / 3, w = mat - sm * 3;
    int t = best_t_for(tm, sm, nullptr);
    const float* src = (w == 0) ? W1 : (w == 1) ? W2 : C1;
    const float* sp = src + (((sm * 4 + t) << 14) + n8 * 16 + l15);
    int k0 = kk * 32 + q * 8;
    s16x8 o;
#pragma unroll
    for (int j = 0; j < 8; ++j) o[j] = (short)f2bf(sp[(k0 + j) * 128]);
    *(s16x8*)(wbf + (size_t)u * 8) = o;
}

// ================= k_fused v3: M=64, 4 blocks/CU (the occupancy round) =================
// R8 null result: halving in-phase work changed nothing -> k_fused is stall/convoy-bound
// (R5 counters: MFMA 7%, VALU 38%, HBM 14%, occ 33%; per-block time ~35us = internal stalls).
// Cure: co-residency. M=64, unfused low-reg skeleton (R5 measured 44 VGPR for this shape),
// per-type Hbuf reuse -> LDS ~34.2 KB, __launch_bounds__(512,8) (64-reg cap) -> 4 blk/CU,
// 32 waves/CU = 2x R8. Per-type weight grouping kept (R6 win). Origin-keyed rot kept
// (R8 proved read conflicts cost ~0). Barriers 2/type; cross-block slack covers them.
__global__ __launch_bounds__(512, 8) void k_fused(
    const float* __restrict__ states, const float* __restrict__ scores,
    const int* __restrict__ type_ids, const float* __restrict__ tm,
    const float* __restrict__ b1g, const float* __restrict__ b2g,
    const float* __restrict__ c1g, const float* __restrict__ C2,
    const float* __restrict__ c2, const unsigned short* __restrict__ wbf,
    float* __restrict__ out_state, float* __restrict__ out_score,
    float* __restrict__ out_prob)
{
    __shared__ __align__(16) unsigned short Abuf[65 * 128];   // 16.25 KB (row 64 = zeros)
    __shared__ __align__(16) unsigned short Hbuf[64 * 128];   // 16 KB, reused per type
    __shared__ int permLds[112];                              // slot -> orig row (-1 = pad)
    __shared__ float pSum[112];
    __shared__ float scoreLds[64];
    __shared__ int wcnt[4];

    const int t = threadIdx.x;
    const int gid0 = blockIdx.x * 64;
    const int lane = t & 63;
    const int wv = t >> 6;            // wave 0..7 -> 16-col slice
    const int l15 = lane & 15;
    const int quad = lane >> 4;
    const int myRow = t >> 3;         // staging: 8 threads/row, 64 rows
    const int q8 = t & 7;
    const int col = wv * 16 + l15;

    int stIdx4[4];
    float bmax[4];
#pragma unroll
    for (int s = 0; s < 4; ++s) stIdx4[s] = s * 4 + best_t_for(tm, s, &bmax[s]);
    float c2v0 = c2[stIdx4[0]], c2v1 = c2[stIdx4[1]];
    float c2v2 = c2[stIdx4[2]], c2v3 = c2[stIdx4[3]];

    if (t < 112) { permLds[t] = -1; pSum[t] = 0.f; }
    if (t >= 448 && t < 464)          // zero row 64 of Abuf (16 threads x 16 B)
        ((int4*)(Abuf + 64 * 128))[t - 448] = int4{0, 0, 0, 0};

    // ---- stage A: 64 dense rows, origin-keyed rot (no partition dependency) ----
    {
        const float4* sp = (const float4*)(states + (size_t)(gid0 + myRow) * 128 + q8 * 16);
        float4 v[4];
#pragma unroll
        for (int i = 0; i < 4; ++i) v[i] = sp[i];
        unsigned short* dstRow = &Abuf[myRow * 128];
        const int rot = (myRow & 15) << 3;
#pragma unroll
        for (int i = 0; i < 4; ++i) {
            int c = (q8 * 16 + i * 4 + rot) & 127;
            ushort4 o;
            o.x = f2bf(v[i].x); o.y = f2bf(v[i].y);
            o.z = f2bf(v[i].z); o.w = f2bf(v[i].w);
            *(ushort4*)(dstRow + c) = o;
        }
    }

    // ---- wave 0: partition 64 rows by ballot (counts uniform in-register) ----
    if (t < 64) {
        int myty = type_ids[gid0 + t];
        scoreLds[t] = scores[gid0 + t];
        unsigned long long msk = 0;
        int c0 = 0, c1 = 0, c2_ = 0, c3 = 0;
        {
            unsigned long long m0 = __ballot(myty == 0);
            unsigned long long m1 = __ballot(myty == 1);
            unsigned long long m2 = __ballot(myty == 2);
            unsigned long long m3 = __ballot(myty == 3);
            msk = (myty == 0) ? m0 : (myty == 1) ? m1 : (myty == 2) ? m2 : m3;
            c0 = (int)__popcll(m0); c1 = (int)__popcll(m1);
            c2_ = (int)__popcll(m2); c3 = (int)__popcll(m3);
        }
        if (t == 0) { wcnt[0] = c0; wcnt[1] = c1; wcnt[2] = c2_; wcnt[3] = c3; }
        int ns0 = (c0 + 15) >> 4, ns1 = (c1 + 15) >> 4, ns2 = (c2_ + 15) >> 4;
        int sb1 = ns0, sb2 = ns0 + ns1, sb3 = ns0 + ns1 + ns2;
        int sbMy = (myty == 0) ? 0 : (myty == 1) ? sb1 : (myty == 2) ? sb2 : sb3;
        unsigned long long lt = (1ull << t) - 1ull;
        permLds[sbMy * 16 + (int)__popcll(msk & lt)] = t;
    }
    __syncthreads();   // B1: Abuf + perm + wcnt + scoreLds ready

    // segment layout (uniform, recomputed per thread from wcnt)
    int nsA[4], sbA[4], G;
    {
        int sb = 0;
#pragma unroll
        for (int sv = 0; sv < 4; ++sv) {
            nsA[sv] = (wcnt[sv] + 15) >> 4;
            sbA[sv] = sb;
            sb += nsA[sv];
        }
        G = sb;   // 4..7
    }

    const unsigned short* __restrict__ wbase = wbf;
    s16x8 wf[4];
    auto loadWf = [&](int ty, int m) {
        const unsigned short* wb = wbase + ((size_t)ty * 3 + m) * 16384;
#pragma unroll
        for (int kk = 0; kk < 4; ++kk)
            wf[kk] = *(const s16x8*)(wb + (size_t)((kk * 8 + wv) * 64 + lane) * 8);
    };
    auto gemmA = [&](int seg) -> f32x4 {
        f32x4 acc = {0.f, 0.f, 0.f, 0.f};
        int pRow = permLds[seg * 16 + l15];
        int rr = (pRow >= 0) ? pRow : 64;
        const unsigned short* ab = Abuf + rr * 128;
        const int rot = (rr & 15) << 3;
#pragma unroll
        for (int kk = 0; kk < 4; ++kk) {
            s16x8 af = *(const s16x8*)(ab + ((kk * 32 + quad * 8 + rot) & 127));
            acc = __builtin_amdgcn_mfma_f32_16x16x32_bf16(af, wf[kk], acc, 0, 0, 0);
        }
        return acc;
    };
    auto gemmH = [&](int si) -> f32x4 {
        f32x4 acc = {0.f, 0.f, 0.f, 0.f};
        const unsigned short* hb = Hbuf + (si * 16 + l15) * 128;
#pragma unroll
        for (int kk = 0; kk < 4; ++kk) {
            s16x8 af = *(const s16x8*)(hb + ((kk * 32 + quad * 8 + (l15 << 3)) & 127));
            acc = __builtin_amdgcn_mfma_f32_16x16x32_bf16(af, wf[kk], acc, 0, 0, 0);
        }
        return acc;
    };

    // ---- per-type: {W1-pass -> Hbuf, C1-pass -> pSum} | barrier | {W2-pass -> out} ----
#pragma unroll
    for (int ty = 0; ty < 4; ++ty) {
        const int ns = nsA[ty];
        if (ns == 0) continue;                 // block-uniform
        const int sb = sbA[ty];
        const int si0 = stIdx4[ty];

        loadWf(ty, 0);                         // W1
        {
            const float b1v = b1g[si0 * 128 + col];
            for (int si = 0; si < ns; ++si) {
                f32x4 a = gemmA(sb + si);
#pragma unroll
                for (int r = 0; r < 4; ++r) {
                    int row = si * 16 + quad * 4 + r;    // local Hbuf row
                    float v = fmaxf(a[r] + b1v, 0.f);
                    Hbuf[row * 128 + ((col + ((row & 15) << 3)) & 127)] = f2bf(v);
                }
            }
        }
        loadWf(ty, 2);                         // C1 (reads Abuf only; no barrier needed yet)
        {
            const float c1v = c1g[si0 * 128 + col];
            const float c2w = C2[si0 * 128 + col];
            for (int si = 0; si < ns; ++si) {
                const int seg = sb + si;
                f32x4 a = gemmA(seg);
                float part[4];
#pragma unroll
                for (int r = 0; r < 4; ++r) part[r] = fmaxf(a[r] + c1v, 0.f) * c2w;
#pragma unroll
                for (int off = 1; off < 16; off <<= 1)
#pragma unroll
                    for (int r = 0; r < 4; ++r) part[r] += __shfl_xor(part[r], off, 64);
                if (l15 == 0) {
#pragma unroll
                    for (int r = 0; r < 4; ++r)
                        atomicAdd(&pSum[seg * 16 + quad * 4 + r], part[r]);
                }
            }
        }
        __syncthreads();                       // Hbuf(ty) complete

        loadWf(ty, 1);                         // W2
        {
            const float b2v = b2g[si0 * 128 + col];
            for (int si = 0; si < ns; ++si) {
                f32x4 a = gemmH(si);
#pragma unroll
                for (int r = 0; r < 4; ++r) {
                    int p = permLds[(sb + si) * 16 + quad * 4 + r];
                    if (p >= 0) out_state[(size_t)(gid0 + p) * 128 + col] = a[r] + b2v;
                }
            }
        }
        __syncthreads();                       // Hbuf free for next type; pSum(ty) visible
    }

    // ---- epilogue: sigmoid, min, score + prob stores ----
    if (t < G * 16) {
        int p = permLds[t];
        if (p >= 0) {
            int seg = t >> 4;
            int sty = (seg >= sbA[1] ? 1 : 0) + (seg >= sbA[2] ? 1 : 0) + (seg >= sbA[3] ? 1 : 0);
            float c2s = (sty == 0) ? c2v0 : (sty == 1) ? c2v1 : (sty == 2) ? c2v2 : c2v3;
            float bm = (sty == 0) ? bmax[0] : (sty == 1) ? bmax[1] : (sty == 2) ? bmax[2] : bmax[3];
            float tot = pSum[t] + c2s;
            float cls = 1.f / (1.f + expf(-tot));
            out_score[gid0 + p] = fminf(scoreLds[p], cls);
            out_prob[gid0 + p] = 1.f / (1.f + expf(-bm));
        }
    }
}

extern "C" void kernel_launch(void* const* d_in, const int* in_sizes, int n_in,
                              void* d_out, int out_size, void* d_ws, size_t ws_size,
                              hipStream_t stream) {
    const float* states = (const float*)d_in[0];
    const float* scores = (const float*)d_in[1];
    const int*   type_ids = (const int*)d_in[2];
    const float* tm = (const float*)d_in[3];
    const float* W1 = (const float*)d_in[4];
    const float* b1 = (const float*)d_in[5];
    const float* W2 = (const float*)d_in[6];
    const float* b2 = (const float*)d_in[7];
    const float* C1 = (const float*)d_in[8];
    const float* c1 = (const float*)d_in[9];
    const float* C2 = (const float*)d_in[10];
    const float* c2 = (const float*)d_in[11];

    unsigned short* wbf = (unsigned short*)d_ws;            // 12 * 16384 bf16, frag-linear

    float* out_state = (float*)d_out;                       // N*128
    float* out_score = out_state + (size_t)Nn * 128;        // N
    float* out_prob  = out_score + Nn;                      // N

    k_prepw<<<96, 256, 0, stream>>>(tm, W1, W2, C1, wbf);
    k_fused<<<1024, 512, 0, stream>>>(states, scores, type_ids, tm, b1, b2, c1,
        C2, c2, wbf, out_state, out_score, out_prob);
}